// Round 5
// baseline (193.868 us; speedup 1.0000x reference)
//
#include <hip/hip_runtime.h>
#include <hip/hip_bf16.h>
#include <math.h>

// VOCAB=50000, EMBED=256, MAXLEN=512, UNITS=32, F1=16, BATCH=512.
#define TT 512
#define BB 512
#define EE 256
#define UU 32
#define FF1 16
#define NWAVE 2048            // proj waves: 8/CU, 2/SIMD (best e2e config, R2)

// 2*log2(e): pre-scale factor so tanh needs no leading multiply.
#define TWO_LOG2E 2.8853900817779268f

__device__ __forceinline__ float rdlane(float v, int lane) {
    return __int_as_float(__builtin_amdgcn_readlane(__float_as_int(v), lane));
}

// v += value from lane (i - N) within the 16-lane DPP row (0 past row edge).
#define DPP_ADD(v, ctrl)                                                    \
    (v) += __int_as_float(__builtin_amdgcn_update_dpp(                      \
        0, __float_as_int(v), (ctrl), 0xf, 0xf, true))

// dst = row_ror:J of srcf (16-lane row rotation, VALU pipe, literal J)
#define RORF(dst, srcf, J)                                                  \
    dst = __int_as_float(__builtin_amdgcn_update_dpp(                       \
        0, __float_as_int(srcf), 0x120 | (J), 0xf, 0xf, true))

// ---------------------------------------------------------------------------
// Kernel A (R2-proven config): P[r][u] = (emb[r]@Wx[:,u] + bias[u])*2log2e.
// DPP-reduce GEMV; ~memory-floor bound.
// ---------------------------------------------------------------------------
__global__ __launch_bounds__(64) void proj_dpp(
    const float* __restrict__ emb, const float* __restrict__ Wx,
    const float* __restrict__ bias, float* __restrict__ P, int nrows)
{
    const int L = threadIdx.x;
    const int g = L >> 4;              // u-octet 0..3
    const int c = L & 15;              // k-lane 0..15
    const int wv = blockIdx.x;         // 0..NWAVE-1

    // ---- one-time coalesced w preload: w[kk][uu] = Wx[c+16*kk][g*8+uu]
    float w[16][8];
    #pragma unroll
    for (int kk = 0; kk < 16; ++kk) {
        const float4* src = (const float4*)(Wx + (size_t)(kk * 16 + c) * UU + g * 8);
        float4 a = src[0], b = src[1];
        w[kk][0] = a.x; w[kk][1] = a.y; w[kk][2] = a.z; w[kk][3] = a.w;
        w[kk][4] = b.x; w[kk][5] = b.y; w[kk][6] = b.z; w[kk][7] = b.w;
    }
    float bs[8];
    #pragma unroll
    for (int uu = 0; uu < 8; ++uu) bs[uu] = bias[g * 8 + uu];

    // rows handled by this wave: r = wv + NWAVE*i
    auto rowptr = [&](int i) {
        int r = wv + NWAVE * i;
        if (r >= nrows) r = nrows - 1;             // clamped dummy
        return emb + (size_t)r * EE;
    };

    float xA[16], xB[16];
    {
        const float* rp = rowptr(0);
        #pragma unroll
        for (int kk = 0; kk < 16; ++kk) xA[kk] = rp[kk * 16 + c];
    }

    const int NI = (nrows - 1 - wv) / NWAVE + 1;   // #valid rows (wv < nrows)

    for (int i = 0; i < NI; ++i) {
        // prefetch next row (clamped at tail)
        {
            const float* rp = rowptr(i + 1 < NI ? i + 1 : i);
            #pragma unroll
            for (int kk = 0; kk < 16; ++kk) xB[kk] = rp[kk * 16 + c];
        }

        // partials for this lane's 16 k's x 8 u's
        float p[8];
        #pragma unroll
        for (int uu = 0; uu < 8; ++uu) p[uu] = 0.f;
        #pragma unroll
        for (int kk = 0; kk < 16; ++kk) {
            const float xk = xA[kk];
            #pragma unroll
            for (int uu = 0; uu < 8; ++uu)
                p[uu] = fmaf(xk, w[kk][uu], p[uu]);
        }

        // reduce over the 16 c-lanes (DPP row-of-16); lane c==15 holds sums
        #pragma unroll
        for (int uu = 0; uu < 8; ++uu) {
            DPP_ADD(p[uu], 0x111);   // row_shr:1
            DPP_ADD(p[uu], 0x112);   // row_shr:2
            DPP_ADD(p[uu], 0x114);   // row_shr:4
            DPP_ADD(p[uu], 0x118);   // row_shr:8
        }

        if (c == 15) {
            const int r = wv + NWAVE * i;
            float4 o0, o1;
            o0.x = (p[0] + bs[0]) * TWO_LOG2E;
            o0.y = (p[1] + bs[1]) * TWO_LOG2E;
            o0.z = (p[2] + bs[2]) * TWO_LOG2E;
            o0.w = (p[3] + bs[3]) * TWO_LOG2E;
            o1.x = (p[4] + bs[4]) * TWO_LOG2E;
            o1.y = (p[5] + bs[5]) * TWO_LOG2E;
            o1.z = (p[6] + bs[6]) * TWO_LOG2E;
            o1.w = (p[7] + bs[7]) * TWO_LOG2E;
            float4* dst = (float4*)(P + (size_t)r * UU + g * 8);
            dst[0] = o0; dst[1] = o1;
        }

        #pragma unroll
        for (int kk = 0; kk < 16; ++kk) xA[kk] = xB[kk];
    }
}

// ---------------------------------------------------------------------------
// Kernel B v11: all-VALU DPP-broadcast scan (no readlane on the chain).
// Theory: v8's ~330cy/step = ~140 issue + ~190 readlane hazards (32x ~6cy
// VGPR->SGPR->VALU wait states). Replace the broadcast with:
//   state layout: lane L holds r_{(L&15)+16*(L>>5)}  (k-halves in 32-halves)
//   1x v_permlane32_swap(r,r) -> A = r_0..15 dup everywhere,
//                                B = r_16..31 dup everywhere
//   15x row_ror:j on A and on B (30 DPP, depth-1, VALU fast-forward)
//   32 FMA with per-lane pre-permuted weights, tree, exp2, rcp.
// row_ror direction resolved by a 1-instr runtime probe (weights indexed by
// kstep), so either ISA convention yields correct results.
// ---------------------------------------------------------------------------
__global__ __launch_bounds__(64) void scan_heads(
    const int* __restrict__ tokens, const float* __restrict__ P,
    const float* __restrict__ Wh,
    const float* __restrict__ W1, const float* __restrict__ b1,
    const float* __restrict__ W2, const float* __restrict__ b2,
    float* __restrict__ out)
{
    __shared__ float xs[TT * UU];      // 512 rows x 128 B = 64 KB

    const int L = threadIdx.x;
    const int c = L & 15;
    const int u = c + ((L >> 5) << 4);   // state/output index this lane owns
    const int b = blockIdx.x;
    const int* trow = tokens + b * TT;

    // ---- probe row_ror direction: ror:1 of lane-id-within-row ----
    // dst[i]=src[(i-1)&15] -> lane0 sees 15 ; dst[i]=src[(i+1)&15] -> sees 1
    int probe = __builtin_amdgcn_update_dpp(0, c, 0x121, 0xf, 0xf, true);
    const int kstep = (__builtin_amdgcn_readfirstlane(probe) == 15) ? -1 : 1;

    // weights: ror_j(A) holds r_{(c+kstep*j)&15}; ror_j(B) the +16 half.
    // wA/wB = -2 * 2log2e * Wh[k][u]  (r-fold: h = 1-2r folded into weights)
    float wA[16], wB[16];
    float S = 0.f;                      // S = sum_k 2log2e*Wh[k][u]
    #pragma unroll
    for (int jj = 0; jj < 16; ++jj) {
        const int kj = (c + kstep * jj) & 15;
        wA[jj] = -2.0f * TWO_LOG2E * Wh[kj * UU + u];
        wB[jj] = -2.0f * TWO_LOG2E * Wh[(16 + kj) * UU + u];
    }
    #pragma unroll
    for (int k = 0; k < UU; ++k) S += TWO_LOG2E * Wh[k * UU + u];

    // ---- gather phase: 64 global_load_lds instrs, 8 tokens each ----
    const int sub = L >> 3;            // token-within-group
    const int q   = L & 7;             // 16-B chunk within the 128-B row
    for (int cc = 0; cc < 8; ++cc) {
        int tk8[8];
        #pragma unroll
        for (int i = 0; i < 8; ++i)
            tk8[i] = trow[cc * 64 + i * 8 + sub];
        #pragma unroll
        for (int i = 0; i < 8; ++i) {
            const float* src = P + (size_t)tk8[i] * UU + q * 4;
            float* dst = xs + (cc * 64 + i * 8) * UU;   // wave-uniform base
            __builtin_amdgcn_global_load_lds(
                (const __attribute__((address_space(1))) void*)src,
                (__attribute__((address_space(3))) void*)dst, 16, 0, 0);
        }
    }
    __syncthreads();   // drains vmcnt: all LDS rows resident

    // ---- scan: pure VALU broadcast ----
    float xr[8];
    #pragma unroll
    for (int j = 0; j < 8; ++j) xr[j] = xs[j * UU + u] + S;

    float r = 0.5f;                    // h = 0  =>  r = 0.5

    for (int t = 0; t < TT; t += 8) {
        // block prefetch: 8 conflict-free ds_read_b32 (+S off-chain)
        float xn[8];
        #pragma unroll
        for (int j = 0; j < 8; ++j)
            xn[j] = xs[((t + 8 + j) & (TT - 1)) * UU + u] + S;

        #pragma unroll
        for (int j = 0; j < 8; ++j) {
            // split state into half-replicated registers (1 VALU swap).
            // r layout: lanes0-31 = [r0..r15,r0..r15], lanes32-63 = r16..31 dup
            // => swap(r,r): ret0 = lo-half dup = r_{c} everywhere,
            //               ret1 = hi-half dup = r_{16+c} everywhere.
            int aI = __float_as_int(r);
            int bI = aI;
            asm("s_nop 1\n\t"
                "v_permlane32_swap_b32 %0, %1\n\t"
                "s_nop 1"
                : "+v"(aI), "+v"(bI));
            float A  = __int_as_float(aI);
            float Bv = __int_as_float(bI);

            float va1, va2, va3, va4, va5, va6, va7, va8,
                  va9, va10, va11, va12, va13, va14, va15;
            float vb1, vb2, vb3, vb4, vb5, vb6, vb7, vb8,
                  vb9, vb10, vb11, vb12, vb13, vb14, vb15;
            RORF(va1,  A, 1);  RORF(va2,  A, 2);  RORF(va3,  A, 3);
            RORF(va4,  A, 4);  RORF(va5,  A, 5);  RORF(va6,  A, 6);
            RORF(va7,  A, 7);  RORF(va8,  A, 8);  RORF(va9,  A, 9);
            RORF(va10, A, 10); RORF(va11, A, 11); RORF(va12, A, 12);
            RORF(va13, A, 13); RORF(va14, A, 14); RORF(va15, A, 15);
            RORF(vb1,  Bv, 1);  RORF(vb2,  Bv, 2);  RORF(vb3,  Bv, 3);
            RORF(vb4,  Bv, 4);  RORF(vb5,  Bv, 5);  RORF(vb6,  Bv, 6);
            RORF(vb7,  Bv, 7);  RORF(vb8,  Bv, 8);  RORF(vb9,  Bv, 9);
            RORF(vb10, Bv, 10); RORF(vb11, Bv, 11); RORF(vb12, Bv, 12);
            RORF(vb13, Bv, 13); RORF(vb14, Bv, 14); RORF(vb15, Bv, 15);

            // 8 accumulators x depth 4
            float p0 = fmaf(A,   wA[0], xr[j]);
            float p1 = va1  * wA[1];
            float p2 = va2  * wA[2];
            float p3 = va3  * wA[3];
            float p4 = va4  * wA[4];
            float p5 = va5  * wA[5];
            float p6 = va6  * wA[6];
            float p7 = va7  * wA[7];
            p0 = fmaf(va8,  wA[8],  p0);
            p1 = fmaf(va9,  wA[9],  p1);
            p2 = fmaf(va10, wA[10], p2);
            p3 = fmaf(va11, wA[11], p3);
            p4 = fmaf(va12, wA[12], p4);
            p5 = fmaf(va13, wA[13], p5);
            p6 = fmaf(va14, wA[14], p6);
            p7 = fmaf(va15, wA[15], p7);
            p0 = fmaf(Bv,   wB[0],  p0);
            p1 = fmaf(vb1,  wB[1],  p1);
            p2 = fmaf(vb2,  wB[2],  p2);
            p3 = fmaf(vb3,  wB[3],  p3);
            p4 = fmaf(vb4,  wB[4],  p4);
            p5 = fmaf(vb5,  wB[5],  p5);
            p6 = fmaf(vb6,  wB[6],  p6);
            p7 = fmaf(vb7,  wB[7],  p7);
            p0 = fmaf(vb8,  wB[8],  p0);
            p1 = fmaf(vb9,  wB[9],  p1);
            p2 = fmaf(vb10, wB[10], p2);
            p3 = fmaf(vb11, wB[11], p3);
            p4 = fmaf(vb12, wB[12], p4);
            p5 = fmaf(vb13, wB[13], p5);
            p6 = fmaf(vb14, wB[14], p6);
            p7 = fmaf(vb15, wB[15], p7);

            float s01 = p0 + p1, s23 = p2 + p3, s45 = p4 + p5, s67 = p6 + p7;
            float e = __builtin_amdgcn_exp2f((s01 + s23) + (s45 + s67));
            r = __builtin_amdgcn_rcpf(e + 1.0f);
            xr[j] = xn[j];
        }
    }

    float h = fmaf(-2.0f, r, 1.0f);    // materialize h once for the heads

    // ---- fused heads (layout-aware: h_k lives at lane (k&15)+((k>>4)<<5)) --
    const int jh = L & 15;
    float s = b1[jh];
    #pragma unroll
    for (int k = 0; k < UU; ++k) {
        float hk = rdlane(h, (k & 15) + ((k >> 4) << 5));
        s = fmaf(hk, W1[k * FF1 + jh], s);
    }
    float z = b2[0];
    #pragma unroll
    for (int jj = 0; jj < FF1; ++jj) {
        float yj = rdlane(s, jj);      // s duplicated across 16-rows
        z = fmaf(yj, W2[jj], z);
    }
    if (L == 0) {
        float e = __builtin_amdgcn_exp2f(-z * 1.4426950408889634f); // e^{-z}
        out[b] = __builtin_amdgcn_rcpf(1.0f + e);
    }
}

// ---------------------------------------------------------------------------
extern "C" void kernel_launch(void* const* d_in, const int* in_sizes, int n_in,
                              void* d_out, int out_size, void* d_ws, size_t ws_size,
                              hipStream_t stream) {
    const int*   tokens = (const int*)  d_in[0];
    const float* emb    = (const float*)d_in[1];
    const float* Wx     = (const float*)d_in[2];
    const float* Wh     = (const float*)d_in[3];
    const float* bias   = (const float*)d_in[4];
    const float* W1     = (const float*)d_in[5];
    const float* b1     = (const float*)d_in[6];
    const float* W2     = (const float*)d_in[7];
    const float* b2     = (const float*)d_in[8];
    float* out = (float*)d_out;

    const int vocab = in_sizes[1] / EE;        // 50000
    float* P = (float*)d_ws;                   // vocab*32*4 = 6.4 MB

    // A: 2048 single-wave blocks, ~25 rows each (8 waves/CU)
    proj_dpp<<<dim3(NWAVE), dim3(64), 0, stream>>>(
        emb, Wx, bias, P, vocab);

    // B: 1 batch row per wave -> 512 blocks x 64 threads (2 blocks/CU)
    scan_heads<<<dim3(BB), dim3(64), 0, stream>>>(
        tokens, P, Wh, W1, b1, W2, b2, out);
}

// Round 6
// 187.734 us; speedup vs baseline: 1.0327x; 1.0327x over previous
//
#include <hip/hip_runtime.h>
#include <hip/hip_bf16.h>
#include <math.h>

// VOCAB=50000, EMBED=256, MAXLEN=512, UNITS=32, F1=16, BATCH=512.
#define TT 512
#define BB 512
#define EE 256
#define UU 32
#define FF1 16
#define NWAVE 2048            // proj waves: 8/CU, 2/SIMD (best e2e config, R2)

// 2*log2(e): pre-scale factor so tanh needs no leading multiply.
#define TWO_LOG2E 2.8853900817779268f

typedef float v2f __attribute__((ext_vector_type(2)));

__device__ __forceinline__ float rdlane(float v, int lane) {
    return __int_as_float(__builtin_amdgcn_readlane(__float_as_int(v), lane));
}

// v += value from lane (i - N) within the 16-lane DPP row (0 past row edge).
#define DPP_ADD(v, ctrl)                                                    \
    (v) += __int_as_float(__builtin_amdgcn_update_dpp(                      \
        0, __float_as_int(v), (ctrl), 0xf, 0xf, true))

// ---------------------------------------------------------------------------
// Kernel A (R2-proven config, unchanged): P[r][u] =
// (emb[r]@Wx[:,u] + bias[u])*2log2e. DPP-reduce GEMV.
// ---------------------------------------------------------------------------
__global__ __launch_bounds__(64) void proj_dpp(
    const float* __restrict__ emb, const float* __restrict__ Wx,
    const float* __restrict__ bias, float* __restrict__ P, int nrows)
{
    const int L = threadIdx.x;
    const int g = L >> 4;              // u-octet 0..3
    const int c = L & 15;              // k-lane 0..15
    const int wv = blockIdx.x;         // 0..NWAVE-1

    // ---- one-time coalesced w preload: w[kk][uu] = Wx[c+16*kk][g*8+uu]
    float w[16][8];
    #pragma unroll
    for (int kk = 0; kk < 16; ++kk) {
        const float4* src = (const float4*)(Wx + (size_t)(kk * 16 + c) * UU + g * 8);
        float4 a = src[0], b = src[1];
        w[kk][0] = a.x; w[kk][1] = a.y; w[kk][2] = a.z; w[kk][3] = a.w;
        w[kk][4] = b.x; w[kk][5] = b.y; w[kk][6] = b.z; w[kk][7] = b.w;
    }
    float bs[8];
    #pragma unroll
    for (int uu = 0; uu < 8; ++uu) bs[uu] = bias[g * 8 + uu];

    // rows handled by this wave: r = wv + NWAVE*i
    auto rowptr = [&](int i) {
        int r = wv + NWAVE * i;
        if (r >= nrows) r = nrows - 1;             // clamped dummy
        return emb + (size_t)r * EE;
    };

    float xA[16], xB[16];
    {
        const float* rp = rowptr(0);
        #pragma unroll
        for (int kk = 0; kk < 16; ++kk) xA[kk] = rp[kk * 16 + c];
    }

    const int NI = (nrows - 1 - wv) / NWAVE + 1;   // #valid rows (wv < nrows)

    for (int i = 0; i < NI; ++i) {
        // prefetch next row (clamped at tail)
        {
            const float* rp = rowptr(i + 1 < NI ? i + 1 : i);
            #pragma unroll
            for (int kk = 0; kk < 16; ++kk) xB[kk] = rp[kk * 16 + c];
        }

        // partials for this lane's 16 k's x 8 u's
        float p[8];
        #pragma unroll
        for (int uu = 0; uu < 8; ++uu) p[uu] = 0.f;
        #pragma unroll
        for (int kk = 0; kk < 16; ++kk) {
            const float xk = xA[kk];
            #pragma unroll
            for (int uu = 0; uu < 8; ++uu)
                p[uu] = fmaf(xk, w[kk][uu], p[uu]);
        }

        // reduce over the 16 c-lanes (DPP row-of-16); lane c==15 holds sums
        #pragma unroll
        for (int uu = 0; uu < 8; ++uu) {
            DPP_ADD(p[uu], 0x111);   // row_shr:1
            DPP_ADD(p[uu], 0x112);   // row_shr:2
            DPP_ADD(p[uu], 0x114);   // row_shr:4
            DPP_ADD(p[uu], 0x118);   // row_shr:8
        }

        if (c == 15) {
            const int r = wv + NWAVE * i;
            float4 o0, o1;
            o0.x = (p[0] + bs[0]) * TWO_LOG2E;
            o0.y = (p[1] + bs[1]) * TWO_LOG2E;
            o0.z = (p[2] + bs[2]) * TWO_LOG2E;
            o0.w = (p[3] + bs[3]) * TWO_LOG2E;
            o1.x = (p[4] + bs[4]) * TWO_LOG2E;
            o1.y = (p[5] + bs[5]) * TWO_LOG2E;
            o1.z = (p[6] + bs[6]) * TWO_LOG2E;
            o1.w = (p[7] + bs[7]) * TWO_LOG2E;
            float4* dst = (float4*)(P + (size_t)r * UU + g * 8);
            dst[0] = o0; dst[1] = o1;
        }

        #pragma unroll
        for (int kk = 0; kk < 16; ++kk) xA[kk] = xB[kk];
    }
}

// ---------------------------------------------------------------------------
// Kernel B v12: packed-FMA scan.
// Model (fits v6/v8/v10/v11): lone wave on a SIMD retires ~1 instr / 4.5cy
// REGARDLESS of dependencies -> time = instr_count x 4.5cy. So: halve the
// instruction count. v_pk_fma_f32 (CDNA packed fp32, exact) does 2 FMAs in
// one instr with an SGPR-PAIR broadcast source (Tensile idiom):
//   32 readlane -> s[40..71], then 4 pk_mul + 12 pk_fma on v2f accs,
//   3 pk_add tree + 2 scalar adds + exp2 + rcp.
// One asm block with explicit physical SGPRs (clobbered) so the compiler
// can't insert mov churn. ~59 instrs/step vs v8's ~71.
// ---------------------------------------------------------------------------
__global__ __launch_bounds__(64) void scan_heads(
    const int* __restrict__ tokens, const float* __restrict__ P,
    const float* __restrict__ Wh,
    const float* __restrict__ W1, const float* __restrict__ b1,
    const float* __restrict__ W2, const float* __restrict__ b2,
    float* __restrict__ out)
{
    __shared__ float xs[TT * UU];      // 512 rows x 128 B = 64 KB

    const int L = threadIdx.x;
    const int u = L & 31;
    const int b = blockIdx.x;
    const int* trow = tokens + b * TT;

    // w2[p] = (wr_{2p}, wr_{2p+1}),  wr_k = -2 * 2log2e * Wh[k][u]  (r-fold)
    // S = sum_k 2log2e*Wh[k][u]  (h = 1-2r folded: a' = x + S + sum r_k*wr_k)
    v2f w2[16];
    float S = 0.f;
    #pragma unroll
    for (int p = 0; p < 16; ++p) {
        float w0 = TWO_LOG2E * Wh[(2 * p) * UU + u];
        float w1 = TWO_LOG2E * Wh[(2 * p + 1) * UU + u];
        S += w0 + w1;
        w2[p].x = -2.0f * w0;
        w2[p].y = -2.0f * w1;
    }

    // ---- gather phase: 64 global_load_lds instrs, 8 tokens each ----
    const int sub = L >> 3;            // token-within-group
    const int q   = L & 7;             // 16-B chunk within the 128-B row
    for (int cc = 0; cc < 8; ++cc) {
        int tk8[8];
        #pragma unroll
        for (int i = 0; i < 8; ++i)
            tk8[i] = trow[cc * 64 + i * 8 + sub];
        #pragma unroll
        for (int i = 0; i < 8; ++i) {
            const float* src = P + (size_t)tk8[i] * UU + q * 4;
            float* dst = xs + (cc * 64 + i * 8) * UU;   // wave-uniform base
            __builtin_amdgcn_global_load_lds(
                (const __attribute__((address_space(1))) void*)src,
                (__attribute__((address_space(3))) void*)dst, 16, 0, 0);
        }
    }
    __syncthreads();   // drains vmcnt: all LDS rows resident

    // ---- scan: packed-FMA VALU ----
    float xr[8];
    #pragma unroll
    for (int j = 0; j < 8; ++j) xr[j] = xs[j * UU + u] + S;

    float r = 0.5f;                    // h = 0  =>  r = 0.5

    for (int t = 0; t < TT; t += 8) {
        // block prefetch: 8 conflict-free ds_read_b32 (+S off-chain)
        float xn[8];
        #pragma unroll
        for (int j = 0; j < 8; ++j)
            xn[j] = xs[((t + 8 + j) & (TT - 1)) * UU + u] + S;

        #pragma unroll
        for (int j = 0; j < 8; ++j) {
            v2f a0, a1, a2, a3;
            // 32 readlanes into s40..s71 (even pairs), then packed dot:
            // acc_{p&3} += (r_{2p},r_{2p+1}) * w2[p]
            asm("s_nop 1\n\t"
                "v_readlane_b32 s40, %4, 0\n\t"
                "v_readlane_b32 s41, %4, 1\n\t"
                "v_readlane_b32 s42, %4, 2\n\t"
                "v_readlane_b32 s43, %4, 3\n\t"
                "v_readlane_b32 s44, %4, 4\n\t"
                "v_readlane_b32 s45, %4, 5\n\t"
                "v_readlane_b32 s46, %4, 6\n\t"
                "v_readlane_b32 s47, %4, 7\n\t"
                "v_readlane_b32 s48, %4, 8\n\t"
                "v_readlane_b32 s49, %4, 9\n\t"
                "v_readlane_b32 s50, %4, 10\n\t"
                "v_readlane_b32 s51, %4, 11\n\t"
                "v_readlane_b32 s52, %4, 12\n\t"
                "v_readlane_b32 s53, %4, 13\n\t"
                "v_readlane_b32 s54, %4, 14\n\t"
                "v_readlane_b32 s55, %4, 15\n\t"
                "v_readlane_b32 s56, %4, 16\n\t"
                "v_readlane_b32 s57, %4, 17\n\t"
                "v_readlane_b32 s58, %4, 18\n\t"
                "v_readlane_b32 s59, %4, 19\n\t"
                "v_readlane_b32 s60, %4, 20\n\t"
                "v_readlane_b32 s61, %4, 21\n\t"
                "v_readlane_b32 s62, %4, 22\n\t"
                "v_readlane_b32 s63, %4, 23\n\t"
                "v_readlane_b32 s64, %4, 24\n\t"
                "v_readlane_b32 s65, %4, 25\n\t"
                "v_readlane_b32 s66, %4, 26\n\t"
                "v_readlane_b32 s67, %4, 27\n\t"
                "v_readlane_b32 s68, %4, 28\n\t"
                "v_readlane_b32 s69, %4, 29\n\t"
                "v_readlane_b32 s70, %4, 30\n\t"
                "v_readlane_b32 s71, %4, 31\n\t"
                "v_pk_mul_f32 %0, s[40:41], %5\n\t"
                "v_pk_mul_f32 %1, s[42:43], %6\n\t"
                "v_pk_mul_f32 %2, s[44:45], %7\n\t"
                "v_pk_mul_f32 %3, s[46:47], %8\n\t"
                "v_pk_fma_f32 %0, s[48:49], %9, %0\n\t"
                "v_pk_fma_f32 %1, s[50:51], %10, %1\n\t"
                "v_pk_fma_f32 %2, s[52:53], %11, %2\n\t"
                "v_pk_fma_f32 %3, s[54:55], %12, %3\n\t"
                "v_pk_fma_f32 %0, s[56:57], %13, %0\n\t"
                "v_pk_fma_f32 %1, s[58:59], %14, %1\n\t"
                "v_pk_fma_f32 %2, s[60:61], %15, %2\n\t"
                "v_pk_fma_f32 %3, s[62:63], %16, %3\n\t"
                "v_pk_fma_f32 %0, s[64:65], %17, %0\n\t"
                "v_pk_fma_f32 %1, s[66:67], %18, %1\n\t"
                "v_pk_fma_f32 %2, s[68:69], %19, %2\n\t"
                "v_pk_fma_f32 %3, s[70:71], %20, %3"
                : "=&v"(a0), "=&v"(a1), "=&v"(a2), "=&v"(a3)
                : "v"(r),
                  "v"(w2[0]),  "v"(w2[1]),  "v"(w2[2]),  "v"(w2[3]),
                  "v"(w2[4]),  "v"(w2[5]),  "v"(w2[6]),  "v"(w2[7]),
                  "v"(w2[8]),  "v"(w2[9]),  "v"(w2[10]), "v"(w2[11]),
                  "v"(w2[12]), "v"(w2[13]), "v"(w2[14]), "v"(w2[15])
                : "s40","s41","s42","s43","s44","s45","s46","s47",
                  "s48","s49","s50","s51","s52","s53","s54","s55",
                  "s56","s57","s58","s59","s60","s61","s62","s63",
                  "s64","s65","s66","s67","s68","s69","s70","s71");

            v2f t01 = a0 + a1;          // v_pk_add_f32
            v2f t23 = a2 + a3;          // v_pk_add_f32
            v2f tt  = t01 + t23;        // v_pk_add_f32
            float a = (tt.x + tt.y) + xr[j];
            float e = __builtin_amdgcn_exp2f(a);
            r = __builtin_amdgcn_rcpf(e + 1.0f);
            xr[j] = xn[j];
        }
    }

    float h = fmaf(-2.0f, r, 1.0f);    // materialize h once for the heads

    // ---- fused heads (once; readlane-only; h replicated in all lanes) ----
    const int j = threadIdx.x & 15;
    float s = b1[j];
    #pragma unroll
    for (int k = 0; k < UU; ++k) {
        float hk = rdlane(h, k);
        s = fmaf(hk, W1[k * FF1 + j], s);
    }
    float z = b2[0];
    #pragma unroll
    for (int jj = 0; jj < FF1; ++jj) {
        float yj = rdlane(s, jj);
        z = fmaf(yj, W2[jj], z);
    }
    if (threadIdx.x == 0) {
        float e = __builtin_amdgcn_exp2f(-z * 1.4426950408889634f); // e^{-z}
        out[b] = __builtin_amdgcn_rcpf(1.0f + e);
    }
}

// ---------------------------------------------------------------------------
extern "C" void kernel_launch(void* const* d_in, const int* in_sizes, int n_in,
                              void* d_out, int out_size, void* d_ws, size_t ws_size,
                              hipStream_t stream) {
    const int*   tokens = (const int*)  d_in[0];
    const float* emb    = (const float*)d_in[1];
    const float* Wx     = (const float*)d_in[2];
    const float* Wh     = (const float*)d_in[3];
    const float* bias   = (const float*)d_in[4];
    const float* W1     = (const float*)d_in[5];
    const float* b1     = (const float*)d_in[6];
    const float* W2     = (const float*)d_in[7];
    const float* b2     = (const float*)d_in[8];
    float* out = (float*)d_out;

    const int vocab = in_sizes[1] / EE;        // 50000
    float* P = (float*)d_ws;                   // vocab*32*4 = 6.4 MB

    // A: 2048 single-wave blocks, ~25 rows each (8 waves/CU)
    proj_dpp<<<dim3(NWAVE), dim3(64), 0, stream>>>(
        emb, Wx, bias, P, vocab);

    // B: 1 batch row per wave -> 512 blocks x 64 threads (2 blocks/CU)
    scan_heads<<<dim3(BB), dim3(64), 0, stream>>>(
        tokens, P, Wh, W1, b1, W2, b2, out);
}

// Round 7
// 183.308 us; speedup vs baseline: 1.0576x; 1.0241x over previous
//
#include <hip/hip_runtime.h>
#include <hip/hip_bf16.h>
#include <math.h>

// VOCAB=50000, EMBED=256, MAXLEN=512, UNITS=32, F1=16, BATCH=512.
#define TT 512
#define BB 512
#define EE 256
#define UU 32
#define FF1 16
#define NWAVE 2048            // proj waves: 8/CU, 2/SIMD (best e2e config, R2)

// 2*log2(e): pre-scale factor so tanh needs no leading multiply.
#define TWO_LOG2E 2.8853900817779268f

__device__ __forceinline__ float rdlane(float v, int lane) {
    return __int_as_float(__builtin_amdgcn_readlane(__float_as_int(v), lane));
}

// v += value from lane (i - N) within the 16-lane DPP row (0 past row edge).
#define DPP_ADD(v, ctrl)                                                    \
    (v) += __int_as_float(__builtin_amdgcn_update_dpp(                      \
        0, __float_as_int(v), (ctrl), 0xf, 0xf, true))

// ---------------------------------------------------------------------------
// Kernel A (R2-proven config): P[r][u] = (emb[r]@Wx[:,u] + bias[u])*2log2e.
// DPP-reduce GEMV; near memory floor. The 2log2e pre-scale moves the tanh
// input scaling off kernel B's serial chain.
// ---------------------------------------------------------------------------
__global__ __launch_bounds__(64) void proj_dpp(
    const float* __restrict__ emb, const float* __restrict__ Wx,
    const float* __restrict__ bias, float* __restrict__ P, int nrows)
{
    const int L = threadIdx.x;
    const int g = L >> 4;              // u-octet 0..3
    const int c = L & 15;              // k-lane 0..15
    const int wv = blockIdx.x;         // 0..NWAVE-1

    // ---- one-time coalesced w preload: w[kk][uu] = Wx[c+16*kk][g*8+uu]
    float w[16][8];
    #pragma unroll
    for (int kk = 0; kk < 16; ++kk) {
        const float4* src = (const float4*)(Wx + (size_t)(kk * 16 + c) * UU + g * 8);
        float4 a = src[0], b = src[1];
        w[kk][0] = a.x; w[kk][1] = a.y; w[kk][2] = a.z; w[kk][3] = a.w;
        w[kk][4] = b.x; w[kk][5] = b.y; w[kk][6] = b.z; w[kk][7] = b.w;
    }
    float bs[8];
    #pragma unroll
    for (int uu = 0; uu < 8; ++uu) bs[uu] = bias[g * 8 + uu];

    // rows handled by this wave: r = wv + NWAVE*i
    auto rowptr = [&](int i) {
        int r = wv + NWAVE * i;
        if (r >= nrows) r = nrows - 1;             // clamped dummy
        return emb + (size_t)r * EE;
    };

    float xA[16], xB[16];
    {
        const float* rp = rowptr(0);
        #pragma unroll
        for (int kk = 0; kk < 16; ++kk) xA[kk] = rp[kk * 16 + c];
    }

    const int NI = (nrows - 1 - wv) / NWAVE + 1;   // #valid rows (wv < nrows)

    for (int i = 0; i < NI; ++i) {
        // prefetch next row (clamped at tail)
        {
            const float* rp = rowptr(i + 1 < NI ? i + 1 : i);
            #pragma unroll
            for (int kk = 0; kk < 16; ++kk) xB[kk] = rp[kk * 16 + c];
        }

        // partials for this lane's 16 k's x 8 u's
        float p[8];
        #pragma unroll
        for (int uu = 0; uu < 8; ++uu) p[uu] = 0.f;
        #pragma unroll
        for (int kk = 0; kk < 16; ++kk) {
            const float xk = xA[kk];
            #pragma unroll
            for (int uu = 0; uu < 8; ++uu)
                p[uu] = fmaf(xk, w[kk][uu], p[uu]);
        }

        // reduce over the 16 c-lanes (DPP row-of-16); lane c==15 holds sums
        #pragma unroll
        for (int uu = 0; uu < 8; ++uu) {
            DPP_ADD(p[uu], 0x111);   // row_shr:1
            DPP_ADD(p[uu], 0x112);   // row_shr:2
            DPP_ADD(p[uu], 0x114);   // row_shr:4
            DPP_ADD(p[uu], 0x118);   // row_shr:8
        }

        if (c == 15) {
            const int r = wv + NWAVE * i;
            float4 o0, o1;
            o0.x = (p[0] + bs[0]) * TWO_LOG2E;
            o0.y = (p[1] + bs[1]) * TWO_LOG2E;
            o0.z = (p[2] + bs[2]) * TWO_LOG2E;
            o0.w = (p[3] + bs[3]) * TWO_LOG2E;
            o1.x = (p[4] + bs[4]) * TWO_LOG2E;
            o1.y = (p[5] + bs[5]) * TWO_LOG2E;
            o1.z = (p[6] + bs[6]) * TWO_LOG2E;
            o1.w = (p[7] + bs[7]) * TWO_LOG2E;
            float4* dst = (float4*)(P + (size_t)r * UU + g * 8);
            dst[0] = o0; dst[1] = o1;
        }

        #pragma unroll
        for (int kk = 0; kk < 16; ++kk) xA[kk] = xB[kk];
    }
}

// ---------------------------------------------------------------------------
// Kernel B v8 (EXACT revert — best measured: 70.2us @ R2).
// h_t = tanh(x_t + h_{t-1} @ Wh); fused heads + sigmoid.
// One batch row per 64-lane wave. Structure is at the measured structural
// floor: per-step = 32 readlane + 32 FMA + tree + exp2 + rcp ≈ 330cy, of
// which ~210 is issue (VALUBusy 32% of 2-of-4 SIMDs = 64%/SIMD) and ~120 is
// irreducible dependency stall. Cheaper-broadcast alternatives all measured
// worse: bpermute +123cy (v7), DPP +47cy (v11), pk-FMA +22cy (v12); multi-
// seq/wave raises wall (issue > stall); fp16 packing breaks tolerance.
// ---------------------------------------------------------------------------
__global__ __launch_bounds__(64) void scan_heads(
    const int* __restrict__ tokens, const float* __restrict__ P,
    const float* __restrict__ Wh,
    const float* __restrict__ W1, const float* __restrict__ b1,
    const float* __restrict__ W2, const float* __restrict__ b2,
    float* __restrict__ out)
{
    __shared__ float xs[TT * UU];      // 512 rows x 128 B = 64 KB

    const int L = threadIdx.x;
    const int u = L & 31;
    const int b = blockIdx.x;
    const int* trow = tokens + b * TT;

    // wh[k] = Wh[k][u] * 2log2e : this lane's column of the recurrent matrix
    float wh[UU];
    #pragma unroll
    for (int k = 0; k < UU; ++k) wh[k] = Wh[k * UU + u] * TWO_LOG2E;

    // ---- gather phase: 64 global_load_lds instrs, 8 tokens each ----
    const int sub = L >> 3;            // token-within-group
    const int q   = L & 7;             // 16-B chunk within the 128-B row
    for (int c = 0; c < 8; ++c) {
        int tk8[8];
        #pragma unroll
        for (int i = 0; i < 8; ++i)
            tk8[i] = trow[c * 64 + i * 8 + sub];
        #pragma unroll
        for (int i = 0; i < 8; ++i) {
            const float* src = P + (size_t)tk8[i] * UU + q * 4;
            float* dst = xs + (c * 64 + i * 8) * UU;    // wave-uniform base
            __builtin_amdgcn_global_load_lds(
                (const __attribute__((address_space(1))) void*)src,
                (__attribute__((address_space(3))) void*)dst, 16, 0, 0);
        }
    }
    __syncthreads();   // drains vmcnt: all LDS rows resident

    // ---- scan: pure LDS + VALU ----
    float xr[8];
    #pragma unroll
    for (int j = 0; j < 8; ++j) xr[j] = xs[j * UU + u];

    float h = 0.f;

    for (int t = 0; t < TT; t += 8) {
        // block prefetch: 8 conflict-free ds_read_b32, consumed 8 steps later
        float xn[8];
        #pragma unroll
        for (int j = 0; j < 8; ++j)
            xn[j] = xs[((t + 8 + j) & (TT - 1)) * UU + u];

        #pragma unroll
        for (int j = 0; j < 8; ++j) {
            // broadcast group: 32 readlanes, one hazard boundary
            float hv[UU];
            #pragma unroll
            for (int k = 0; k < UU; ++k) hv[k] = rdlane(h, k);

            float a0 = fmaf(hv[0], wh[0], xr[j]);   // x folded into acc0
            float a1 = hv[1] * wh[1];
            float a2 = hv[2] * wh[2];
            float a3 = hv[3] * wh[3];
            #pragma unroll
            for (int k = 4; k < UU; k += 4) {
                a0 = fmaf(hv[k],     wh[k],     a0);
                a1 = fmaf(hv[k + 1], wh[k + 1], a1);
                a2 = fmaf(hv[k + 2], wh[k + 2], a2);
                a3 = fmaf(hv[k + 3], wh[k + 3], a3);
            }
            // pre-scaled input: tanh(a) = 1 - 2/(exp2(a')+1), a' = 2log2e*a
            float e = __builtin_amdgcn_exp2f((a0 + a1) + (a2 + a3));
            float r = __builtin_amdgcn_rcpf(e + 1.0f);
            h = fmaf(-2.0f, r, 1.0f);
            xr[j] = xn[j];
        }
    }

    // ---- fused heads (once; readlane-only; h replicated in all lanes) ----
    const int j = threadIdx.x & 15;
    float s = b1[j];
    #pragma unroll
    for (int k = 0; k < UU; ++k) {
        float hk = rdlane(h, k);
        s = fmaf(hk, W1[k * FF1 + j], s);
    }
    float z = b2[0];
    #pragma unroll
    for (int jj = 0; jj < FF1; ++jj) {
        float yj = rdlane(s, jj);
        z = fmaf(yj, W2[jj], z);
    }
    if (threadIdx.x == 0) {
        float e = __builtin_amdgcn_exp2f(-z * 1.4426950408889634f); // e^{-z}
        out[b] = __builtin_amdgcn_rcpf(1.0f + e);
    }
}

// ---------------------------------------------------------------------------
extern "C" void kernel_launch(void* const* d_in, const int* in_sizes, int n_in,
                              void* d_out, int out_size, void* d_ws, size_t ws_size,
                              hipStream_t stream) {
    const int*   tokens = (const int*)  d_in[0];
    const float* emb    = (const float*)d_in[1];
    const float* Wx     = (const float*)d_in[2];
    const float* Wh     = (const float*)d_in[3];
    const float* bias   = (const float*)d_in[4];
    const float* W1     = (const float*)d_in[5];
    const float* b1     = (const float*)d_in[6];
    const float* W2     = (const float*)d_in[7];
    const float* b2     = (const float*)d_in[8];
    float* out = (float*)d_out;

    const int vocab = in_sizes[1] / EE;        // 50000
    float* P = (float*)d_ws;                   // vocab*32*4 = 6.4 MB

    // A: 2048 single-wave blocks, ~25 rows each (8 waves/CU)
    proj_dpp<<<dim3(NWAVE), dim3(64), 0, stream>>>(
        emb, Wx, bias, P, vocab);

    // B: 1 batch row per wave -> 512 blocks x 64 threads (2 blocks/CU)
    scan_heads<<<dim3(BB), dim3(64), 0, stream>>>(
        tokens, P, Wh, W1, b1, W2, b2, out);
}

// Round 8
// 175.250 us; speedup vs baseline: 1.1062x; 1.0460x over previous
//
#include <hip/hip_runtime.h>
#include <hip/hip_bf16.h>
#include <math.h>

// VOCAB=50000, EMBED=256, MAXLEN=512, UNITS=32, F1=16, BATCH=512.
#define TT 512
#define BB 512
#define EE 256
#define UU 32
#define FF1 16
#define NWAVE 2048            // proj waves: 8/CU, 2/SIMD (best e2e config, R2)

// 2*log2(e): pre-scale factor so tanh needs no leading multiply.
#define TWO_LOG2E 2.8853900817779268f

__device__ __forceinline__ float rdlane(float v, int lane) {
    return __int_as_float(__builtin_amdgcn_readlane(__float_as_int(v), lane));
}

// v += value from lane (i - N) within the 16-lane DPP row (0 past row edge).
#define DPP_ADD(v, ctrl)                                                    \
    (v) += __int_as_float(__builtin_amdgcn_update_dpp(                      \
        0, __float_as_int(v), (ctrl), 0xf, 0xf, true))

// ---------------------------------------------------------------------------
// Kernel A (R2-proven config, unchanged): P[r][u] =
// (emb[r]@Wx[:,u] + bias[u])*2log2e. DPP-reduce GEMV; near memory floor.
// ---------------------------------------------------------------------------
__global__ __launch_bounds__(64) void proj_dpp(
    const float* __restrict__ emb, const float* __restrict__ Wx,
    const float* __restrict__ bias, float* __restrict__ P, int nrows)
{
    const int L = threadIdx.x;
    const int g = L >> 4;              // u-octet 0..3
    const int c = L & 15;              // k-lane 0..15
    const int wv = blockIdx.x;         // 0..NWAVE-1

    // ---- one-time coalesced w preload: w[kk][uu] = Wx[c+16*kk][g*8+uu]
    float w[16][8];
    #pragma unroll
    for (int kk = 0; kk < 16; ++kk) {
        const float4* src = (const float4*)(Wx + (size_t)(kk * 16 + c) * UU + g * 8);
        float4 a = src[0], b = src[1];
        w[kk][0] = a.x; w[kk][1] = a.y; w[kk][2] = a.z; w[kk][3] = a.w;
        w[kk][4] = b.x; w[kk][5] = b.y; w[kk][6] = b.z; w[kk][7] = b.w;
    }
    float bs[8];
    #pragma unroll
    for (int uu = 0; uu < 8; ++uu) bs[uu] = bias[g * 8 + uu];

    // rows handled by this wave: r = wv + NWAVE*i
    auto rowptr = [&](int i) {
        int r = wv + NWAVE * i;
        if (r >= nrows) r = nrows - 1;             // clamped dummy
        return emb + (size_t)r * EE;
    };

    float xA[16], xB[16];
    {
        const float* rp = rowptr(0);
        #pragma unroll
        for (int kk = 0; kk < 16; ++kk) xA[kk] = rp[kk * 16 + c];
    }

    const int NI = (nrows - 1 - wv) / NWAVE + 1;   // #valid rows (wv < nrows)

    for (int i = 0; i < NI; ++i) {
        // prefetch next row (clamped at tail)
        {
            const float* rp = rowptr(i + 1 < NI ? i + 1 : i);
            #pragma unroll
            for (int kk = 0; kk < 16; ++kk) xB[kk] = rp[kk * 16 + c];
        }

        // partials for this lane's 16 k's x 8 u's
        float p[8];
        #pragma unroll
        for (int uu = 0; uu < 8; ++uu) p[uu] = 0.f;
        #pragma unroll
        for (int kk = 0; kk < 16; ++kk) {
            const float xk = xA[kk];
            #pragma unroll
            for (int uu = 0; uu < 8; ++uu)
                p[uu] = fmaf(xk, w[kk][uu], p[uu]);
        }

        // reduce over the 16 c-lanes (DPP row-of-16); lane c==15 holds sums
        #pragma unroll
        for (int uu = 0; uu < 8; ++uu) {
            DPP_ADD(p[uu], 0x111);   // row_shr:1
            DPP_ADD(p[uu], 0x112);   // row_shr:2
            DPP_ADD(p[uu], 0x114);   // row_shr:4
            DPP_ADD(p[uu], 0x118);   // row_shr:8
        }

        if (c == 15) {
            const int r = wv + NWAVE * i;
            float4 o0, o1;
            o0.x = (p[0] + bs[0]) * TWO_LOG2E;
            o0.y = (p[1] + bs[1]) * TWO_LOG2E;
            o0.z = (p[2] + bs[2]) * TWO_LOG2E;
            o0.w = (p[3] + bs[3]) * TWO_LOG2E;
            o1.x = (p[4] + bs[4]) * TWO_LOG2E;
            o1.y = (p[5] + bs[5]) * TWO_LOG2E;
            o1.z = (p[6] + bs[6]) * TWO_LOG2E;
            o1.w = (p[7] + bs[7]) * TWO_LOG2E;
            float4* dst = (float4*)(P + (size_t)r * UU + g * 8);
            dst[0] = o0; dst[1] = o1;
        }

        #pragma unroll
        for (int kk = 0; kk < 16; ++kk) xA[kk] = xB[kk];
    }
}

// ---------------------------------------------------------------------------
// Kernel B v13: DPP-FUSED-FMA scan — the broadcast costs ZERO instructions.
// Model (6 data points): time ≈ instrs x ~4.5cy + ~120cy fixed stall. v8's 71
// instrs/step = 32 readlane + 32 FMA + tail. v13 fuses the rotation INTO the
// FMA via VOP2+DPP (v_fmac_f32 acc, A, w row_ror:j), eliminating all 32
// broadcast instructions: ~45 instrs/step.
// All risky machinery is v11-HW-verified (absmax 0.0): permlane32_swap
// semantics, lane layout u=(L&15)+16*(L>>5), row_ror direction probe with
// kstep-indexed weights, s_nop padding, layout-aware heads. Only the encoding
// of the rotation moved (standalone mov_dpp -> fused src-modifier).
// Hazards: DPP-read-after-VALU-write needs 2 wait states; only A/B are ever
// DPP-read, each written once by the swap, padded s_nop 1 + a non-DPP VOP3
// before the first DPP consumer. Accs are never DPP operands.
// ---------------------------------------------------------------------------
__global__ __launch_bounds__(64) void scan_heads(
    const int* __restrict__ tokens, const float* __restrict__ P,
    const float* __restrict__ Wh,
    const float* __restrict__ W1, const float* __restrict__ b1,
    const float* __restrict__ W2, const float* __restrict__ b2,
    float* __restrict__ out)
{
    __shared__ float xs[TT * UU];      // 512 rows x 128 B = 64 KB

    const int L = threadIdx.x;
    const int c = L & 15;
    const int u = c + ((L >> 5) << 4);   // state/output index this lane owns
    const int b = blockIdx.x;
    const int* trow = tokens + b * TT;

    // ---- probe row_ror direction (v11-verified): ror:1 of lane-in-row ----
    int probe = __builtin_amdgcn_update_dpp(0, c, 0x121, 0xf, 0xf, true);
    const int kstep = (__builtin_amdgcn_readfirstlane(probe) == 15) ? -1 : 1;

    // weights: ror_j(A) at lane c holds h_{(c+kstep*j)&15}; ror_j(B) the +16
    // half.  wA/wB = 2log2e * Wh[k][u]  (x from P already pre-scaled).
    float wA[16], wB[16];
    #pragma unroll
    for (int jj = 0; jj < 16; ++jj) {
        const int kj = (c + kstep * jj) & 15;
        wA[jj] = TWO_LOG2E * Wh[kj * UU + u];
        wB[jj] = TWO_LOG2E * Wh[(16 + kj) * UU + u];
    }

    // ---- gather phase: 64 global_load_lds instrs, 8 tokens each ----
    const int sub = L >> 3;            // token-within-group
    const int q   = L & 7;             // 16-B chunk within the 128-B row
    for (int cc = 0; cc < 8; ++cc) {
        int tk8[8];
        #pragma unroll
        for (int i = 0; i < 8; ++i)
            tk8[i] = trow[cc * 64 + i * 8 + sub];
        #pragma unroll
        for (int i = 0; i < 8; ++i) {
            const float* src = P + (size_t)tk8[i] * UU + q * 4;
            float* dst = xs + (cc * 64 + i * 8) * UU;   // wave-uniform base
            __builtin_amdgcn_global_load_lds(
                (const __attribute__((address_space(1))) void*)src,
                (__attribute__((address_space(3))) void*)dst, 16, 0, 0);
        }
    }
    __syncthreads();   // drains vmcnt: all LDS rows resident

    // ---- scan ----
    float xr[8];
    #pragma unroll
    for (int j = 0; j < 8; ++j) xr[j] = xs[j * UU + u];

    float h = 0.f;

    for (int t = 0; t < TT; t += 8) {
        // block prefetch: 8 conflict-free ds_read_b32, consumed 8 steps later
        float xn[8];
        #pragma unroll
        for (int j = 0; j < 8; ++j)
            xn[j] = xs[((t + 8 + j) & (TT - 1)) * UU + u];

        #pragma unroll
        for (int j = 0; j < 8; ++j) {
            // h layout: lanes0-31 = [h0..h15,h0..h15], lanes32-63 = h16..h31
            // dup.  swap(A,B) (A=B=h):  A = h_c in every 16-row,
            //                           B = h_{16+c} in every 16-row.
            float A  = h;
            float Bv = h;
            asm("s_nop 1\n\t"
                "v_permlane32_swap_b32 %0, %1\n\t"
                "s_nop 1"
                : "+v"(A), "+v"(Bv));

            // A-half: 16 terms, rotation fused into the FMA (zero-cost bcast)
            float a0, a1, a2, a3;
            asm("v_fma_f32  %0, %4, %6, %5\n\t"
                "v_mul_f32  %1, %4, %7  row_ror:1\n\t"
                "v_mul_f32  %2, %4, %8  row_ror:2\n\t"
                "v_mul_f32  %3, %4, %9  row_ror:3\n\t"
                "v_fmac_f32 %0, %4, %10 row_ror:4\n\t"
                "v_fmac_f32 %1, %4, %11 row_ror:5\n\t"
                "v_fmac_f32 %2, %4, %12 row_ror:6\n\t"
                "v_fmac_f32 %3, %4, %13 row_ror:7\n\t"
                "v_fmac_f32 %0, %4, %14 row_ror:8\n\t"
                "v_fmac_f32 %1, %4, %15 row_ror:9\n\t"
                "v_fmac_f32 %2, %4, %16 row_ror:10\n\t"
                "v_fmac_f32 %3, %4, %17 row_ror:11\n\t"
                "v_fmac_f32 %0, %4, %18 row_ror:12\n\t"
                "v_fmac_f32 %1, %4, %19 row_ror:13\n\t"
                "v_fmac_f32 %2, %4, %20 row_ror:14\n\t"
                "v_fmac_f32 %3, %4, %21 row_ror:15"
                : "=&v"(a0), "=&v"(a1), "=&v"(a2), "=&v"(a3)
                : "v"(A), "v"(xr[j]),
                  "v"(wA[0]),  "v"(wA[1]),  "v"(wA[2]),  "v"(wA[3]),
                  "v"(wA[4]),  "v"(wA[5]),  "v"(wA[6]),  "v"(wA[7]),
                  "v"(wA[8]),  "v"(wA[9]),  "v"(wA[10]), "v"(wA[11]),
                  "v"(wA[12]), "v"(wA[13]), "v"(wA[14]), "v"(wA[15]));

            // B-half: 16 more terms into the same accumulators
            asm("v_fmac_f32 %0, %4, %5\n\t"
                "v_fmac_f32 %1, %4, %6  row_ror:1\n\t"
                "v_fmac_f32 %2, %4, %7  row_ror:2\n\t"
                "v_fmac_f32 %3, %4, %8  row_ror:3\n\t"
                "v_fmac_f32 %0, %4, %9  row_ror:4\n\t"
                "v_fmac_f32 %1, %4, %10 row_ror:5\n\t"
                "v_fmac_f32 %2, %4, %11 row_ror:6\n\t"
                "v_fmac_f32 %3, %4, %12 row_ror:7\n\t"
                "v_fmac_f32 %0, %4, %13 row_ror:8\n\t"
                "v_fmac_f32 %1, %4, %14 row_ror:9\n\t"
                "v_fmac_f32 %2, %4, %15 row_ror:10\n\t"
                "v_fmac_f32 %3, %4, %16 row_ror:11\n\t"
                "v_fmac_f32 %0, %4, %17 row_ror:12\n\t"
                "v_fmac_f32 %1, %4, %18 row_ror:13\n\t"
                "v_fmac_f32 %2, %4, %19 row_ror:14\n\t"
                "v_fmac_f32 %3, %4, %20 row_ror:15"
                : "+v"(a0), "+v"(a1), "+v"(a2), "+v"(a3)
                : "v"(Bv),
                  "v"(wB[0]),  "v"(wB[1]),  "v"(wB[2]),  "v"(wB[3]),
                  "v"(wB[4]),  "v"(wB[5]),  "v"(wB[6]),  "v"(wB[7]),
                  "v"(wB[8]),  "v"(wB[9]),  "v"(wB[10]), "v"(wB[11]),
                  "v"(wB[12]), "v"(wB[13]), "v"(wB[14]), "v"(wB[15]));

            // tail: tanh(a) = 1 - 2/(exp2(a')+1)  (a' pre-scaled by 2log2e)
            float e = __builtin_amdgcn_exp2f((a0 + a1) + (a2 + a3));
            float r = __builtin_amdgcn_rcpf(e + 1.0f);
            h = fmaf(-2.0f, r, 1.0f);
            xr[j] = xn[j];
        }
    }

    // ---- fused heads (layout-aware: h_k lives at lane (k&15)+((k>>4)<<5)) --
    const int jh = L & 15;
    float s = b1[jh];
    #pragma unroll
    for (int k = 0; k < UU; ++k) {
        float hk = rdlane(h, (k & 15) + ((k >> 4) << 5));
        s = fmaf(hk, W1[k * FF1 + jh], s);
    }
    float z = b2[0];
    #pragma unroll
    for (int jj = 0; jj < FF1; ++jj) {
        float yj = rdlane(s, jj);      // s duplicated across 16-rows
        z = fmaf(yj, W2[jj], z);
    }
    if (L == 0) {
        float e = __builtin_amdgcn_exp2f(-z * 1.4426950408889634f); // e^{-z}
        out[b] = __builtin_amdgcn_rcpf(1.0f + e);
    }
}

// ---------------------------------------------------------------------------
extern "C" void kernel_launch(void* const* d_in, const int* in_sizes, int n_in,
                              void* d_out, int out_size, void* d_ws, size_t ws_size,
                              hipStream_t stream) {
    const int*   tokens = (const int*)  d_in[0];
    const float* emb    = (const float*)d_in[1];
    const float* Wx     = (const float*)d_in[2];
    const float* Wh     = (const float*)d_in[3];
    const float* bias   = (const float*)d_in[4];
    const float* W1     = (const float*)d_in[5];
    const float* b1     = (const float*)d_in[6];
    const float* W2     = (const float*)d_in[7];
    const float* b2     = (const float*)d_in[8];
    float* out = (float*)d_out;

    const int vocab = in_sizes[1] / EE;        // 50000
    float* P = (float*)d_ws;                   // vocab*32*4 = 6.4 MB

    // A: 2048 single-wave blocks, ~25 rows each (8 waves/CU)
    proj_dpp<<<dim3(NWAVE), dim3(64), 0, stream>>>(
        emb, Wx, bias, P, vocab);

    // B: 1 batch row per wave -> 512 blocks x 64 threads (2 blocks/CU)
    scan_heads<<<dim3(BB), dim3(64), 0, stream>>>(
        tokens, P, Wh, W1, b1, W2, b2, out);
}